// Round 3
// baseline (1327.018 us; speedup 1.0000x reference)
//
#include <hip/hip_runtime.h>

#define T_TOK 2048
#define HDIM  1024
#define FDIM  512
#define NEXP  64
#define TOPK  8
#define NGRP  8
#define TGRP  4
#define CAPC  1024
#define SCALE_F 2.5f

typedef _Float16 f16;
typedef _Float16 f16x4 __attribute__((ext_vector_type(4)));
typedef _Float16 f16x8 __attribute__((ext_vector_type(8)));
typedef float    f32x4 __attribute__((ext_vector_type(4)));

typedef const __attribute__((address_space(1))) void* gas_t;
typedef __attribute__((address_space(3))) void* las_t;
__device__ __forceinline__ void gl2lds16(const void* g, void* l) {
    __builtin_amdgcn_global_load_lds((gas_t)g, (las_t)l, 16, 0, 0);
}
// XOR-swizzled fragment read: logical (row r, 16B-seg s) -> phys seg s^(r&7)
#define FRAG(S, r, s) (*(const f16x8*)&S[(r)*64 + (((s) ^ ((r)&7)))*8])

__device__ __forceinline__ f16x8 cvt8(float4 a, float4 b) {
    f16x8 h = { (f16)a.x, (f16)a.y, (f16)a.z, (f16)a.w,
                (f16)b.x, (f16)b.y, (f16)b.z, (f16)b.w };
    return h;
}

// ---------------------------------------------------------------------------
// fp32 -> f16 streaming conversion (8 elems/thread) — used only for x.
// ---------------------------------------------------------------------------
__global__ void k_cvt(const float* __restrict__ src, f16* __restrict__ dst, int n8)
{
    int i = blockIdx.x * blockDim.x + threadIdx.x;
    if (i >= n8) return;
    const float4* s = (const float4*)src + (size_t)i * 2;
    float4 a = s[0], b = s[1];
    *(f16x8*)(dst + (size_t)i * 8) = cvt8(a, b);
}

// ---------------------------------------------------------------------------
// Logits GEMM (fp32): logits[T,64] = x[T,H] . gw[64,H]^T
// ---------------------------------------------------------------------------
__global__ __launch_bounds__(256) void k_logits(const float* __restrict__ x,
                                                const float* __restrict__ gw,
                                                float* __restrict__ logits)
{
    __shared__ float sX[8][132];
    __shared__ float sGW[64][132];
    int tid = threadIdx.x;
    int t0 = blockIdx.x * 8;
    int tl = tid & 7;
    int eb = tid >> 3;
    f32x4 acc0 = {0.f,0.f,0.f,0.f}, acc1 = {0.f,0.f,0.f,0.f};

    for (int hc0 = 0; hc0 < HDIM; hc0 += 128) {
        __syncthreads();
        {
            int row = tid >> 5, c4 = tid & 31;
            float4 v = *(const float4*)(x + (size_t)(t0 + row) * HDIM + hc0 + c4 * 4);
            *(float4*)&sX[row][c4 * 4] = v;
        }
        #pragma unroll
        for (int k = 0; k < 8; ++k) {
            int row = k * 8 + (tid >> 5), c4 = tid & 31;
            float4 v = *(const float4*)(gw + (size_t)row * HDIM + hc0 + c4 * 4);
            *(float4*)&sGW[row][c4 * 4] = v;
        }
        __syncthreads();
        #pragma unroll
        for (int c4 = 0; c4 < 32; ++c4) {
            float4 ax = *(const float4*)&sX[tl][c4 * 4];
            float4 g0 = *(const float4*)&sGW[eb][c4 * 4];
            float4 g1 = *(const float4*)&sGW[eb + 32][c4 * 4];
            acc0.x += ax.x * g0.x; acc0.y += ax.y * g0.y;
            acc0.z += ax.z * g0.z; acc0.w += ax.w * g0.w;
            acc1.x += ax.x * g1.x; acc1.y += ax.y * g1.y;
            acc1.z += ax.z * g1.z; acc1.w += ax.w * g1.w;
        }
    }
    float l0 = (acc0.x + acc0.y) + (acc0.z + acc0.w);
    float l1 = (acc1.x + acc1.y) + (acc1.z + acc1.w);
    logits[(size_t)(t0 + tl) * NEXP + eb]      = l0;
    logits[(size_t)(t0 + tl) * NEXP + eb + 32] = l1;
}

// ---------------------------------------------------------------------------
// Top-k per token
// ---------------------------------------------------------------------------
__global__ void k_topk(const float* __restrict__ logits, const float* __restrict__ ebias,
                       int* __restrict__ counts,
                       int* __restrict__ slot_e, int* __restrict__ slot_pos,
                       float* __restrict__ slot_w)
{
    int t = blockIdx.x;
    int lane = threadIdx.x;
    __shared__ float sS[NEXP], sF[NEXP];
    __shared__ float gsc[NGRP];
    __shared__ unsigned gmask_s;
    __shared__ int sIdx[TOPK];

    float logit = logits[(size_t)t * NEXP + lane];
    float score = 1.f / (1.f + __expf(-logit));
    float sfc = score + ebias[lane];
    sS[lane] = score; sF[lane] = sfc;
    __syncthreads();

    if (lane < NGRP) {
        float m1 = -1e30f, m2 = -1e30f;
        for (int j = 0; j < NEXP / NGRP; ++j) {
            float v = sF[lane * (NEXP / NGRP) + j];
            if (v > m1) { m2 = m1; m1 = v; } else if (v > m2) m2 = v;
        }
        gsc[lane] = m1 + m2;
    }
    __syncthreads();
    if (lane == 0) {
        unsigned gm = 0;
        for (int s = 0; s < TGRP; ++s) {
            float best = -1e30f; int bg = 0;
            for (int g = 0; g < NGRP; ++g)
                if (!((gm >> g) & 1) && gsc[g] > best) { best = gsc[g]; bg = g; }
            gm |= 1u << bg;
        }
        gmask_s = gm;
    }
    __syncthreads();

    float vv = ((gmask_s >> (lane >> 3)) & 1) ? sfc : 0.0f;
    for (int k = 0; k < TOPK; ++k) {
        float bv = vv; int bi = lane;
        for (int off = 32; off; off >>= 1) {
            float ov = __shfl_down(bv, off);
            int   oi = __shfl_down(bi, off);
            if (ov > bv || (ov == bv && oi < bi)) { bv = ov; bi = oi; }
        }
        bi = __shfl(bi, 0);
        if (lane == bi) vv = -1e30f;
        if (lane == 0) sIdx[k] = bi;
    }
    __syncthreads();
    if (lane == 0) {
        float sum = 0.f;
        for (int k = 0; k < TOPK; ++k) sum += sS[sIdx[k]];
        float inv = SCALE_F / (sum + 1e-20f);
        for (int k = 0; k < TOPK; ++k) {
            int e = sIdx[k];
            int pos = atomicAdd(&counts[e], 1);
            int s = t * TOPK + k;
            slot_e[s] = e; slot_pos[s] = pos; slot_w[s] = sS[e] * inv;
        }
    }
}

__global__ void k_scan(const int* __restrict__ counts, int* __restrict__ offsets)
{
    if (threadIdx.x == 0) {
        int s = 0;
        for (int e = 0; e < NEXP; ++e) { offsets[e] = s; s += counts[e]; }
    }
}

__global__ void k_rowmap(const int* __restrict__ slot_e, const int* __restrict__ slot_pos,
                         const int* __restrict__ offsets, int* __restrict__ row_tok)
{
    int s = blockIdx.x * 256 + threadIdx.x;
    if (s >= T_TOK * TOPK) return;
    int p = slot_pos[s];
    if (p >= CAPC) return;
    row_tok[offsets[slot_e[s]] + p] = s >> 3;
}

// ---------------------------------------------------------------------------
// Fused gate-up GEMM: H = silu(A.W1^T) * (A.W3^T).
// BM=256 (W read ONCE per expert: no y-tile dup), BN=64, 512 thr / 8 waves.
// A f16 gl2lds into single-buffered sA; W fp32 reg-staged (double-buffered
// in REGISTERS, prefetched one K-step ahead) + fused cvt + swizzled ds_write.
// LDS 48 KB.
// ---------------------------------------------------------------------------
__global__ __launch_bounds__(512, 4) void k_gateup(
    const f16* __restrict__ A, const float* __restrict__ W1,
    const float* __restrict__ W3, f16* __restrict__ Hout,
    const int* __restrict__ offsets, const int* __restrict__ counts,
    const int* __restrict__ row_tok,
    int K, int Nld, int Mtot, int expert_mode)
{
    int e = expert_mode ? blockIdx.z : 0;
    int rowbeg = expert_mode ? offsets[e] : 0;
    int M = expert_mode ? (counts[e] < CAPC ? counts[e] : CAPC) : Mtot;
    int mtile = blockIdx.y * 256;
    if (mtile >= M) return;
    int Mblk = M - mtile; if (Mblk > 256) Mblk = 256;
    int n0 = blockIdx.x * 64;
    const float* W1e = W1 + (size_t)e * Nld * K;
    const float* W3e = W3 + (size_t)e * Nld * K;

    __shared__ __align__(16) f16 sA[256 * 64];   // 32 KB (single, gl2lds)
    __shared__ __align__(16) f16 sB1[64 * 64];   // 8 KB (reg-staged)
    __shared__ __align__(16) f16 sB3[64 * 64];   // 8 KB

    int tid = threadIdx.x, wave = tid >> 6, lane = tid & 63;
    int subrow = lane >> 3;
    int lseg = (lane & 7) ^ subrow;

    // A: 32 rows/wave via 4 gl2lds units (8 rows each)
    const f16* aptr[4];
    #pragma unroll
    for (int c = 0; c < 4; ++c) {
        int r = (wave * 4 + c) * 8 + subrow;
        int rr = (r < Mblk) ? r : 0;
        size_t srow = expert_mode ? (size_t)row_tok[rowbeg + mtile + rr]
                                  : (size_t)(rowbeg + mtile + rr);
        aptr[c] = A + srow * (size_t)K + lseg * 8;
    }
    // W: 8 rows/wave/mat (one LDS unit each)
    const float* w1p = W1e + (size_t)(n0 + wave * 8 + subrow) * K + lseg * 8;
    const float* w3p = W3e + (size_t)(n0 + wave * 8 + subrow) * K + lseg * 8;

    int lrow = lane & 15, lquad = lane >> 4;
    int wm = (wave >> 1) * 64, wn = (wave & 1) * 32;

    f32x4 accg[4][2], accu[4][2];
    #pragma unroll
    for (int i = 0; i < 4; ++i)
        #pragma unroll
        for (int j = 0; j < 2; ++j) {
            f32x4 z = {0.f, 0.f, 0.f, 0.f};
            accg[i][j] = z; accu[i][j] = z;
        }

    // two named register sets for W (static indexing, rule: no dynamic idx)
    float4 a1_0, a1_1, a3_0, a3_1;   // set A
    float4 b1_0, b1_1, b3_0, b3_1;   // set B

    auto stageA = [&](int k0) {
        #pragma unroll
        for (int c = 0; c < 4; ++c)
            gl2lds16(aptr[c] + k0, &sA[(wave * 4 + c) * 512]);
    };
    auto compute = [&]() {
        #pragma unroll
        for (int ks = 0; ks < 2; ++ks) {
            int seg = ks * 4 + lquad;
            f16x8 a[4], b1[2], b3[2];
            #pragma unroll
            for (int i = 0; i < 4; ++i) a[i] = FRAG(sA, wm + i * 16 + lrow, seg);
            #pragma unroll
            for (int j = 0; j < 2; ++j) {
                b1[j] = FRAG(sB1, wn + j * 16 + lrow, seg);
                b3[j] = FRAG(sB3, wn + j * 16 + lrow, seg);
            }
            #pragma unroll
            for (int i = 0; i < 4; ++i)
                #pragma unroll
                for (int j = 0; j < 2; ++j) {
                    accg[i][j] = __builtin_amdgcn_mfma_f32_16x16x32_f16(a[i], b1[j], accg[i][j], 0, 0, 0);
                    accu[i][j] = __builtin_amdgcn_mfma_f32_16x16x32_f16(a[i], b3[j], accu[i][j], 0, 0, 0);
                }
        }
    };

    // prologue: W set A <- k=0
    a1_0 = *(const float4*)(w1p);     a1_1 = *(const float4*)(w1p + 4);
    a3_0 = *(const float4*)(w3p);     a3_1 = *(const float4*)(w3p + 4);

    // main loop unrolled by 2 (K/64 is even) for static set alternation
    for (int k0 = 0; k0 < K; k0 += 128) {
        // W set B <- k0+64 (in flight across first compute)
        b1_0 = *(const float4*)(w1p + k0 + 64); b1_1 = *(const float4*)(w1p + k0 + 68);
        b3_0 = *(const float4*)(w3p + k0 + 64); b3_1 = *(const float4*)(w3p + k0 + 68);
        // write set A (loaded >=1 compute-phase ago), stage A tile k0
        *(f16x8*)&sB1[wave * 512 + lane * 8] = cvt8(a1_0, a1_1);
        *(f16x8*)&sB3[wave * 512 + lane * 8] = cvt8(a3_0, a3_1);
        stageA(k0);
        __syncthreads();      // drains gl2lds(A) + ds_write(W)
        compute();
        __syncthreads();      // everyone done reading sA/sB
        if (k0 + 128 < K) {
            a1_0 = *(const float4*)(w1p + k0 + 128); a1_1 = *(const float4*)(w1p + k0 + 132);
            a3_0 = *(const float4*)(w3p + k0 + 128); a3_1 = *(const float4*)(w3p + k0 + 132);
        }
        *(f16x8*)&sB1[wave * 512 + lane * 8] = cvt8(b1_0, b1_1);
        *(f16x8*)&sB3[wave * 512 + lane * 8] = cvt8(b3_0, b3_1);
        stageA(k0 + 64);
        __syncthreads();
        compute();
        __syncthreads();
    }

    f16* Hrow = Hout + (size_t)(rowbeg + mtile) * Nld + n0;
    #pragma unroll
    for (int i = 0; i < 4; ++i)
        #pragma unroll
        for (int j = 0; j < 2; ++j)
            #pragma unroll
            for (int r = 0; r < 4; ++r) {
                int m = wm + i * 16 + lquad * 4 + r;
                if (m < Mblk) {
                    int n = wn + j * 16 + lrow;
                    float g = accg[i][j][r], u = accu[i][j][r];
                    float h = g / (1.f + __expf(-g)) * u;
                    Hrow[(size_t)m * Nld + n] = (f16)h;
                }
            }
}

// ---------------------------------------------------------------------------
// Down GEMM: Y = A.W^T. BM=256, BN=128, 512 thr / 8 waves.
// A f16 gl2lds single-buffered; W fp32 reg-dbuf + fused cvt. LDS 48 KB.
// ---------------------------------------------------------------------------
__global__ __launch_bounds__(512, 4) void k_down(
    const f16* __restrict__ A, const float* __restrict__ W,
    f16* __restrict__ Y,
    const int* __restrict__ offsets, const int* __restrict__ counts,
    int K, int Nld, int Mtot, int expert_mode)
{
    int e = expert_mode ? blockIdx.z : 0;
    int rowbeg = expert_mode ? offsets[e] : 0;
    int M = expert_mode ? (counts[e] < CAPC ? counts[e] : CAPC) : Mtot;
    int mtile = blockIdx.y * 256;
    if (mtile >= M) return;
    int Mblk = M - mtile; if (Mblk > 256) Mblk = 256;
    int n0 = blockIdx.x * 128;
    const float* We = W + (size_t)e * Nld * K;

    __shared__ __align__(16) f16 sA[256 * 64];   // 32 KB
    __shared__ __align__(16) f16 sW[128 * 64];   // 16 KB

    int tid = threadIdx.x, wave = tid >> 6, lane = tid & 63;
    int subrow = lane >> 3;
    int lseg = (lane & 7) ^ subrow;

    const f16* aptr[4];
    #pragma unroll
    for (int c = 0; c < 4; ++c) {
        int r = (wave * 4 + c) * 8 + subrow;
        int rr = (r < Mblk) ? r : 0;
        aptr[c] = A + (size_t)(rowbeg + mtile + rr) * K + lseg * 8;
    }
    // W: 16 rows/wave via 2 units
    const float* wp0 = We + (size_t)(n0 + (wave * 2 + 0) * 8 + subrow) * K + lseg * 8;
    const float* wp1 = We + (size_t)(n0 + (wave * 2 + 1) * 8 + subrow) * K + lseg * 8;

    int lrow = lane & 15, lquad = lane >> 4;
    int wm = (wave >> 1) * 64, wn = (wave & 1) * 64;

    f32x4 acc[4][4];
    #pragma unroll
    for (int i = 0; i < 4; ++i)
        #pragma unroll
        for (int j = 0; j < 4; ++j) { f32x4 z = {0.f, 0.f, 0.f, 0.f}; acc[i][j] = z; }

    float4 aw0_0, aw0_1, aw1_0, aw1_1;   // set A (unit0, unit1)
    float4 bw0_0, bw0_1, bw1_0, bw1_1;   // set B

    auto stageA = [&](int k0) {
        #pragma unroll
        for (int c = 0; c < 4; ++c)
            gl2lds16(aptr[c] + k0, &sA[(wave * 4 + c) * 512]);
    };
    auto compute = [&]() {
        #pragma unroll
        for (int ks = 0; ks < 2; ++ks) {
            int seg = ks * 4 + lquad;
            f16x8 a[4], bb[4];
            #pragma unroll
            for (int i = 0; i < 4; ++i) a[i]  = FRAG(sA, wm + i * 16 + lrow, seg);
            #pragma unroll
            for (int j = 0; j < 4; ++j) bb[j] = FRAG(sW, wn + j * 16 + lrow, seg);
            #pragma unroll
            for (int i = 0; i < 4; ++i)
                #pragma unroll
                for (int j = 0; j < 4; ++j)
                    acc[i][j] = __builtin_amdgcn_mfma_f32_16x16x32_f16(a[i], bb[j], acc[i][j], 0, 0, 0);
        }
    };

    aw0_0 = *(const float4*)(wp0);     aw0_1 = *(const float4*)(wp0 + 4);
    aw1_0 = *(const float4*)(wp1);     aw1_1 = *(const float4*)(wp1 + 4);

    for (int k0 = 0; k0 < K; k0 += 128) {
        bw0_0 = *(const float4*)(wp0 + k0 + 64); bw0_1 = *(const float4*)(wp0 + k0 + 68);
        bw1_0 = *(const float4*)(wp1 + k0 + 64); bw1_1 = *(const float4*)(wp1 + k0 + 68);
        *(f16x8*)&sW[(wave * 2 + 0) * 512 + lane * 8] = cvt8(aw0_0, aw0_1);
        *(f16x8*)&sW[(wave * 2 + 1) * 512 + lane * 8] = cvt8(aw1_0, aw1_1);
        stageA(k0);
        __syncthreads();
        compute();
        __syncthreads();
        if (k0 + 128 < K) {
            aw0_0 = *(const float4*)(wp0 + k0 + 128); aw0_1 = *(const float4*)(wp0 + k0 + 132);
            aw1_0 = *(const float4*)(wp1 + k0 + 128); aw1_1 = *(const float4*)(wp1 + k0 + 132);
        }
        *(f16x8*)&sW[(wave * 2 + 0) * 512 + lane * 8] = cvt8(bw0_0, bw0_1);
        *(f16x8*)&sW[(wave * 2 + 1) * 512 + lane * 8] = cvt8(bw1_0, bw1_1);
        stageA(k0 + 64);
        __syncthreads();
        compute();
        __syncthreads();
    }

    f16* Yrow = Y + (size_t)(rowbeg + mtile) * Nld + n0;
    #pragma unroll
    for (int i = 0; i < 4; ++i)
        #pragma unroll
        for (int j = 0; j < 4; ++j)
            #pragma unroll
            for (int r = 0; r < 4; ++r) {
                int m = wm + i * 16 + lquad * 4 + r;
                if (m < Mblk)
                    Yrow[(size_t)m * Nld + wn + j * 16 + lrow] = (f16)acc[i][j][r];
            }
}

// ---------------------------------------------------------------------------
// Combine: out[t] = ys[t] + sum_k w_k * y[row(t,k)]
// ---------------------------------------------------------------------------
__global__ void k_combine(const f16* __restrict__ y, const f16* __restrict__ ys,
                          const int* __restrict__ slot_e, const int* __restrict__ slot_pos,
                          const float* __restrict__ slot_w, const int* __restrict__ offsets,
                          float* __restrict__ out)
{
    int t = blockIdx.x, i = threadIdx.x;
    size_t col = (size_t)i * 4;
    f16x4 s = *(const f16x4*)(ys + (size_t)t * HDIM + col);
    float a0 = (float)s[0], a1 = (float)s[1], a2 = (float)s[2], a3 = (float)s[3];
    #pragma unroll
    for (int k = 0; k < TOPK; ++k) {
        int sidx = t * TOPK + k;
        int p = slot_pos[sidx];
        if (p < CAPC) {
            int row = offsets[slot_e[sidx]] + p;
            float w = slot_w[sidx];
            f16x4 v = *(const f16x4*)(y + (size_t)row * HDIM + col);
            a0 += w * (float)v[0]; a1 += w * (float)v[1];
            a2 += w * (float)v[2]; a3 += w * (float)v[3];
        }
    }
    float4 o = {a0, a1, a2, a3};
    *(float4*)(out + (size_t)t * HDIM + col) = o;
}

extern "C" void kernel_launch(void* const* d_in, const int* in_sizes, int n_in,
                              void* d_out, int out_size, void* d_ws, size_t ws_size,
                              hipStream_t stream)
{
    const float* x  = (const float*)d_in[0];
    const float* gw = (const float*)d_in[1];
    const float* eb = (const float*)d_in[2];
    const float* w1 = (const float*)d_in[3];
    const float* w2 = (const float*)d_in[4];
    const float* w3 = (const float*)d_in[5];
    const float* sg = (const float*)d_in[6];
    const float* su = (const float*)d_in[7];
    const float* sd = (const float*)d_in[8];
    float* out = (float*)d_out;

    char* p = (char*)d_ws;
    size_t off = 0;
    auto alloc = [&](size_t n) { void* r = p + off; off = (off + n + 255) & ~(size_t)255; return r; };
    int*   counts   = (int*)alloc(NEXP * 4);
    int*   offsets  = (int*)alloc(NEXP * 4);
    int*   slot_e   = (int*)alloc((size_t)T_TOK * TOPK * 4);
    int*   slot_pos = (int*)alloc((size_t)T_TOK * TOPK * 4);
    float* slot_w   = (float*)alloc((size_t)T_TOK * TOPK * 4);
    int*   row_tok  = (int*)alloc((size_t)T_TOK * TOPK * 4);
    float* logits   = (float*)alloc((size_t)T_TOK * NEXP * 4);          // 512 KB
    f16*   xb  = (f16*)alloc((size_t)T_TOK * HDIM * 2);                 // 4 MB
    f16*   h   = (f16*)alloc((size_t)T_TOK * TOPK * FDIM * 2);          // 16 MB
    f16*   y   = (f16*)alloc((size_t)T_TOK * TOPK * HDIM * 2);          // 32 MB
    f16*   hs  = (f16*)alloc((size_t)T_TOK * 2 * FDIM * 2);             // 4 MB
    f16*   ys  = (f16*)alloc((size_t)T_TOK * HDIM * 2);                 // 4 MB

    hipMemsetAsync(counts, 0, NEXP * 4, stream);

    // routing path
    const int XW8 = T_TOK * HDIM / 8;            // 262144
    k_cvt<<<(XW8 + 255) / 256, 256, 0, stream>>>(x, xb, XW8);
    k_logits<<<T_TOK / 8, 256, 0, stream>>>(x, gw, logits);
    k_topk<<<T_TOK, 64, 0, stream>>>(logits, eb, counts, slot_e, slot_pos, slot_w);
    k_scan<<<1, 64, 0, stream>>>(counts, offsets);
    k_rowmap<<<(T_TOK * TOPK + 255) / 256, 256, 0, stream>>>(slot_e, slot_pos, offsets, row_tok);

    // gate-up GEMMs (weights fp32, conversion fused into staging)
    k_gateup<<<dim3(FDIM / 64, CAPC / 256, NEXP), 512, 0, stream>>>(
        xb, w1, w3, h, offsets, counts, row_tok, HDIM, FDIM, 0, 1);
    k_gateup<<<dim3((2 * FDIM) / 64, T_TOK / 256, 1), 512, 0, stream>>>(
        xb, sg, su, hs, offsets, counts, row_tok, HDIM, 2 * FDIM, T_TOK, 0);

    // down GEMMs
    k_down<<<dim3(HDIM / 128, CAPC / 256, NEXP), 512, 0, stream>>>(
        h, w2, y, offsets, counts, FDIM, HDIM, 0, 1);
    k_down<<<dim3(HDIM / 128, T_TOK / 256, 1), 512, 0, stream>>>(
        hs, sd, ys, offsets, counts, 2 * FDIM, HDIM, T_TOK, 0);

    k_combine<<<T_TOK, 256, 0, stream>>>(y, ys, slot_e, slot_pos, slot_w, offsets, out);
}

// Round 4
// 653.450 us; speedup vs baseline: 2.0308x; 2.0308x over previous
//
#include <hip/hip_runtime.h>

#define T_TOK 2048
#define HDIM  1024
#define FDIM  512
#define NEXP  64
#define TOPK  8
#define NGRP  8
#define TGRP  4
#define CAPC  1024
#define SCALE_F 2.5f

typedef _Float16 f16;
typedef _Float16 f16x4 __attribute__((ext_vector_type(4)));
typedef _Float16 f16x8 __attribute__((ext_vector_type(8)));
typedef float    f32x4 __attribute__((ext_vector_type(4)));

typedef const __attribute__((address_space(1))) void* gas_t;
typedef __attribute__((address_space(3))) void* las_t;
__device__ __forceinline__ void gl2lds16(const void* g, void* l) {
    __builtin_amdgcn_global_load_lds((gas_t)g, (las_t)l, 16, 0, 0);
}
// XOR-swizzled fragment read: logical (row r, 16B-seg s) -> phys seg s^(r&7)
#define FRAG(S, r, s) (*(const f16x8*)&S[(r)*64 + (((s) ^ ((r)&7)))*8])

__device__ __forceinline__ f16x8 cvt8(float4 a, float4 b) {
    f16x8 h = { (f16)a.x, (f16)a.y, (f16)a.z, (f16)a.w,
                (f16)b.x, (f16)b.y, (f16)b.z, (f16)b.w };
    return h;
}

// ---------------------------------------------------------------------------
// fp32 -> f16 streaming conversion (8 elems/thread) — used only for x.
// ---------------------------------------------------------------------------
__global__ void k_cvt(const float* __restrict__ src, f16* __restrict__ dst, int n8)
{
    int i = blockIdx.x * blockDim.x + threadIdx.x;
    if (i >= n8) return;
    const float4* s = (const float4*)src + (size_t)i * 2;
    float4 a = s[0], b = s[1];
    *(f16x8*)(dst + (size_t)i * 8) = cvt8(a, b);
}

// ---------------------------------------------------------------------------
// Logits GEMM (fp32): logits[T,64] = x[T,H] . gw[64,H]^T
// ---------------------------------------------------------------------------
__global__ __launch_bounds__(256) void k_logits(const float* __restrict__ x,
                                                const float* __restrict__ gw,
                                                float* __restrict__ logits)
{
    __shared__ float sX[8][132];
    __shared__ float sGW[64][132];
    int tid = threadIdx.x;
    int t0 = blockIdx.x * 8;
    int tl = tid & 7;
    int eb = tid >> 3;
    f32x4 acc0 = {0.f,0.f,0.f,0.f}, acc1 = {0.f,0.f,0.f,0.f};

    for (int hc0 = 0; hc0 < HDIM; hc0 += 128) {
        __syncthreads();
        {
            int row = tid >> 5, c4 = tid & 31;
            float4 v = *(const float4*)(x + (size_t)(t0 + row) * HDIM + hc0 + c4 * 4);
            *(float4*)&sX[row][c4 * 4] = v;
        }
        #pragma unroll
        for (int k = 0; k < 8; ++k) {
            int row = k * 8 + (tid >> 5), c4 = tid & 31;
            float4 v = *(const float4*)(gw + (size_t)row * HDIM + hc0 + c4 * 4);
            *(float4*)&sGW[row][c4 * 4] = v;
        }
        __syncthreads();
        #pragma unroll
        for (int c4 = 0; c4 < 32; ++c4) {
            float4 ax = *(const float4*)&sX[tl][c4 * 4];
            float4 g0 = *(const float4*)&sGW[eb][c4 * 4];
            float4 g1 = *(const float4*)&sGW[eb + 32][c4 * 4];
            acc0.x += ax.x * g0.x; acc0.y += ax.y * g0.y;
            acc0.z += ax.z * g0.z; acc0.w += ax.w * g0.w;
            acc1.x += ax.x * g1.x; acc1.y += ax.y * g1.y;
            acc1.z += ax.z * g1.z; acc1.w += ax.w * g1.w;
        }
    }
    float l0 = (acc0.x + acc0.y) + (acc0.z + acc0.w);
    float l1 = (acc1.x + acc1.y) + (acc1.z + acc1.w);
    logits[(size_t)(t0 + tl) * NEXP + eb]      = l0;
    logits[(size_t)(t0 + tl) * NEXP + eb + 32] = l1;
}

// ---------------------------------------------------------------------------
// Top-k per token
// ---------------------------------------------------------------------------
__global__ void k_topk(const float* __restrict__ logits, const float* __restrict__ ebias,
                       int* __restrict__ counts,
                       int* __restrict__ slot_e, int* __restrict__ slot_pos,
                       float* __restrict__ slot_w)
{
    int t = blockIdx.x;
    int lane = threadIdx.x;
    __shared__ float sS[NEXP], sF[NEXP];
    __shared__ float gsc[NGRP];
    __shared__ unsigned gmask_s;
    __shared__ int sIdx[TOPK];

    float logit = logits[(size_t)t * NEXP + lane];
    float score = 1.f / (1.f + __expf(-logit));
    float sfc = score + ebias[lane];
    sS[lane] = score; sF[lane] = sfc;
    __syncthreads();

    if (lane < NGRP) {
        float m1 = -1e30f, m2 = -1e30f;
        for (int j = 0; j < NEXP / NGRP; ++j) {
            float v = sF[lane * (NEXP / NGRP) + j];
            if (v > m1) { m2 = m1; m1 = v; } else if (v > m2) m2 = v;
        }
        gsc[lane] = m1 + m2;
    }
    __syncthreads();
    if (lane == 0) {
        unsigned gm = 0;
        for (int s = 0; s < TGRP; ++s) {
            float best = -1e30f; int bg = 0;
            for (int g = 0; g < NGRP; ++g)
                if (!((gm >> g) & 1) && gsc[g] > best) { best = gsc[g]; bg = g; }
            gm |= 1u << bg;
        }
        gmask_s = gm;
    }
    __syncthreads();

    float vv = ((gmask_s >> (lane >> 3)) & 1) ? sfc : 0.0f;
    for (int k = 0; k < TOPK; ++k) {
        float bv = vv; int bi = lane;
        for (int off = 32; off; off >>= 1) {
            float ov = __shfl_down(bv, off);
            int   oi = __shfl_down(bi, off);
            if (ov > bv || (ov == bv && oi < bi)) { bv = ov; bi = oi; }
        }
        bi = __shfl(bi, 0);
        if (lane == bi) vv = -1e30f;
        if (lane == 0) sIdx[k] = bi;
    }
    __syncthreads();
    if (lane == 0) {
        float sum = 0.f;
        for (int k = 0; k < TOPK; ++k) sum += sS[sIdx[k]];
        float inv = SCALE_F / (sum + 1e-20f);
        for (int k = 0; k < TOPK; ++k) {
            int e = sIdx[k];
            int pos = atomicAdd(&counts[e], 1);
            int s = t * TOPK + k;
            slot_e[s] = e; slot_pos[s] = pos; slot_w[s] = sS[e] * inv;
        }
    }
}

__global__ void k_scan(const int* __restrict__ counts, int* __restrict__ offsets)
{
    if (threadIdx.x == 0) {
        int s = 0;
        for (int e = 0; e < NEXP; ++e) { offsets[e] = s; s += counts[e]; }
    }
}

__global__ void k_rowmap(const int* __restrict__ slot_e, const int* __restrict__ slot_pos,
                         const int* __restrict__ offsets, int* __restrict__ row_tok)
{
    int s = blockIdx.x * 256 + threadIdx.x;
    if (s >= T_TOK * TOPK) return;
    int p = slot_pos[s];
    if (p >= CAPC) return;
    row_tok[offsets[slot_e[s]] + p] = s >> 3;
}

// ---------------------------------------------------------------------------
// Fused gate-up GEMM: H = silu(A.W1^T) * (A.W3^T).
// A f16, gl2lds-staged into double-buffered sA. W1/W3 fp32, reg-staged with
// fused fp32->f16 cvt + swizzled ds_write into SINGLE-buffered sB.
// LDS total 48 KB.
// GRID (expert mode): (ntile, expert, mtile) so that ACTIVE blocks occupy
// CONTIGUOUS linear dispatch IDs (dead mtile>=M blocks trail at the end) —
// avoids periodic dead-block patterns concentrating work on a subset of CUs.
// ---------------------------------------------------------------------------
__global__ __launch_bounds__(256, 3) void k_gateup(
    const f16* __restrict__ A, const float* __restrict__ W1,
    const float* __restrict__ W3, f16* __restrict__ Hout,
    const int* __restrict__ offsets, const int* __restrict__ counts,
    const int* __restrict__ row_tok,
    int K, int Nld, int Mtot, int expert_mode)
{
    int e = expert_mode ? blockIdx.y : 0;
    int rowbeg = expert_mode ? offsets[e] : 0;
    int M = expert_mode ? (counts[e] < CAPC ? counts[e] : CAPC) : Mtot;
    int mtile = (expert_mode ? blockIdx.z : blockIdx.y) * 128;
    if (mtile >= M) return;
    int Mblk = M - mtile; if (Mblk > 128) Mblk = 128;
    int n0 = blockIdx.x * 64;
    const float* W1e = W1 + (size_t)e * Nld * K;
    const float* W3e = W3 + (size_t)e * Nld * K;

    __shared__ __align__(16) f16 sA[2][128 * 64];   // 32 KB (dbuf, gl2lds)
    __shared__ __align__(16) f16 sB1[64 * 64];      // 8 KB (single, reg-staged)
    __shared__ __align__(16) f16 sB3[64 * 64];      // 8 KB

    int tid = threadIdx.x, wave = tid >> 6, lane = tid & 63;
    int subrow = lane >> 3;
    int lseg = (lane & 7) ^ subrow;

    const f16* aptr[4];
    #pragma unroll
    for (int c = 0; c < 4; ++c) {
        int r = (wave * 4 + c) * 8 + subrow;
        int rr = (r < Mblk) ? r : 0;
        size_t srow = expert_mode ? (size_t)row_tok[rowbeg + mtile + rr]
                                  : (size_t)(rowbeg + mtile + rr);
        aptr[c] = A + srow * (size_t)K + lseg * 8;
    }
    const float *w1p[2], *w3p[2];
    #pragma unroll
    for (int c = 0; c < 2; ++c) {
        int r = (wave * 2 + c) * 8 + subrow;
        w1p[c] = W1e + (size_t)(n0 + r) * K + lseg * 8;
        w3p[c] = W3e + (size_t)(n0 + r) * K + lseg * 8;
    }

    int lrow = lane & 15, lquad = lane >> 4;
    int wm = (wave & 1) * 64, wn = (wave >> 1) * 32;

    f32x4 accg[4][2], accu[4][2];
    #pragma unroll
    for (int i = 0; i < 4; ++i)
        #pragma unroll
        for (int j = 0; j < 2; ++j) {
            f32x4 z = {0.f, 0.f, 0.f, 0.f};
            accg[i][j] = z; accu[i][j] = z;
        }

    float4 r1[2][2], r3[2][2];   // in-flight fp32 weight tile (registers)

    auto loadW = [&](int k0) {
        #pragma unroll
        for (int c = 0; c < 2; ++c) {
            r1[c][0] = *(const float4*)(w1p[c] + k0);
            r1[c][1] = *(const float4*)(w1p[c] + k0 + 4);
            r3[c][0] = *(const float4*)(w3p[c] + k0);
            r3[c][1] = *(const float4*)(w3p[c] + k0 + 4);
        }
    };
    auto stageA = [&](int k0, int b) {
        #pragma unroll
        for (int c = 0; c < 4; ++c)
            gl2lds16(aptr[c] + k0, &sA[b][(wave * 4 + c) * 512]);
    };
    auto writeW = [&]() {
        #pragma unroll
        for (int c = 0; c < 2; ++c) {
            *(f16x8*)&sB1[(wave * 2 + c) * 512 + lane * 8] = cvt8(r1[c][0], r1[c][1]);
            *(f16x8*)&sB3[(wave * 2 + c) * 512 + lane * 8] = cvt8(r3[c][0], r3[c][1]);
        }
    };
    auto compute = [&](int b) {
        const f16* cA = sA[b];
        #pragma unroll
        for (int ks = 0; ks < 2; ++ks) {
            int seg = ks * 4 + lquad;
            f16x8 a[4], b1[2], b3[2];
            #pragma unroll
            for (int i = 0; i < 4; ++i) a[i] = FRAG(cA, wm + i * 16 + lrow, seg);
            #pragma unroll
            for (int j = 0; j < 2; ++j) {
                b1[j] = FRAG(sB1, wn + j * 16 + lrow, seg);
                b3[j] = FRAG(sB3, wn + j * 16 + lrow, seg);
            }
            #pragma unroll
            for (int i = 0; i < 4; ++i)
                #pragma unroll
                for (int j = 0; j < 2; ++j) {
                    accg[i][j] = __builtin_amdgcn_mfma_f32_16x16x32_f16(a[i], b1[j], accg[i][j], 0, 0, 0);
                    accu[i][j] = __builtin_amdgcn_mfma_f32_16x16x32_f16(a[i], b3[j], accu[i][j], 0, 0, 0);
                }
        }
    };

    // prologue: W loads first (counted vmcnt before writeW), then A gl2lds
    loadW(0);
    stageA(0, 0);
    writeW();
    __syncthreads();          // drains gl2lds(A0) + ds_writes(W0)

    int cb = 0;
    for (int k0 = 64; k0 < K; k0 += 64) {
        loadW(k0);            // next fp32 W -> regs (issued FIRST)
        stageA(k0, cb ^ 1);   // next A gl2lds -> other buffer (stays in flight)
        compute(cb);          // MFMAs on current tile (global loads in flight)
        __syncthreads();      // all waves done reading sB
        writeW();             // cvt + swizzled ds_write
        __syncthreads();      // sB visible; gl2lds(A next) drained
        cb ^= 1;
    }
    compute(cb);

    f16* Hrow = Hout + (size_t)(rowbeg + mtile) * Nld + n0;
    #pragma unroll
    for (int i = 0; i < 4; ++i)
        #pragma unroll
        for (int j = 0; j < 2; ++j)
            #pragma unroll
            for (int r = 0; r < 4; ++r) {
                int m = wm + i * 16 + lquad * 4 + r;
                if (m < Mblk) {
                    int n = wn + j * 16 + lrow;
                    float g = accg[i][j][r], u = accu[i][j][r];
                    float h = g / (1.f + __expf(-g)) * u;
                    Hrow[(size_t)m * Nld + n] = (f16)h;
                }
            }
}

// ---------------------------------------------------------------------------
// Down GEMM: Y = A.W^T. A f16 gl2lds (dbuf); W fp32 reg-staged + fused cvt
// into single-buffered sW. LDS 48 KB. Same contiguous-active grid layout.
// ---------------------------------------------------------------------------
__global__ __launch_bounds__(256, 3) void k_down(
    const f16* __restrict__ A, const float* __restrict__ W,
    f16* __restrict__ Y,
    const int* __restrict__ offsets, const int* __restrict__ counts,
    int K, int Nld, int Mtot, int expert_mode)
{
    int e = expert_mode ? blockIdx.y : 0;
    int rowbeg = expert_mode ? offsets[e] : 0;
    int M = expert_mode ? (counts[e] < CAPC ? counts[e] : CAPC) : Mtot;
    int mtile = (expert_mode ? blockIdx.z : blockIdx.y) * 128;
    if (mtile >= M) return;
    int Mblk = M - mtile; if (Mblk > 128) Mblk = 128;
    int n0 = blockIdx.x * 128;
    const float* We = W + (size_t)e * Nld * K;

    __shared__ __align__(16) f16 sA[2][128 * 64];   // 32 KB
    __shared__ __align__(16) f16 sW[128 * 64];      // 16 KB

    int tid = threadIdx.x, wave = tid >> 6, lane = tid & 63;
    int subrow = lane >> 3;
    int lseg = (lane & 7) ^ subrow;

    const f16* aptr[4];
    const float* wp[4];
    #pragma unroll
    for (int c = 0; c < 4; ++c) {
        int r = (wave * 4 + c) * 8 + subrow;
        int rr = (r < Mblk) ? r : 0;
        aptr[c] = A + (size_t)(rowbeg + mtile + rr) * K + lseg * 8;
        wp[c]   = We + (size_t)(n0 + r) * K + lseg * 8;
    }

    int lrow = lane & 15, lquad = lane >> 4;
    int wm = (wave & 1) * 64, wn = (wave >> 1) * 64;

    f32x4 acc[4][4];
    #pragma unroll
    for (int i = 0; i < 4; ++i)
        #pragma unroll
        for (int j = 0; j < 4; ++j) { f32x4 z = {0.f, 0.f, 0.f, 0.f}; acc[i][j] = z; }

    float4 wr[4][2];

    auto loadW = [&](int k0) {
        #pragma unroll
        for (int c = 0; c < 4; ++c) {
            wr[c][0] = *(const float4*)(wp[c] + k0);
            wr[c][1] = *(const float4*)(wp[c] + k0 + 4);
        }
    };
    auto stageA = [&](int k0, int b) {
        #pragma unroll
        for (int c = 0; c < 4; ++c)
            gl2lds16(aptr[c] + k0, &sA[b][(wave * 4 + c) * 512]);
    };
    auto writeW = [&]() {
        #pragma unroll
        for (int c = 0; c < 4; ++c)
            *(f16x8*)&sW[(wave * 4 + c) * 512 + lane * 8] = cvt8(wr[c][0], wr[c][1]);
    };
    auto compute = [&](int b) {
        const f16* cA = sA[b];
        #pragma unroll
        for (int ks = 0; ks < 2; ++ks) {
            int seg = ks * 4 + lquad;
            f16x8 a[4], bb[4];
            #pragma unroll
            for (int i = 0; i < 4; ++i) a[i]  = FRAG(cA, wm + i * 16 + lrow, seg);
            #pragma unroll
            for (int j = 0; j < 4; ++j) bb[j] = FRAG(sW, wn + j * 16 + lrow, seg);
            #pragma unroll
            for (int i = 0; i < 4; ++i)
                #pragma unroll
                for (int j = 0; j < 4; ++j)
                    acc[i][j] = __builtin_amdgcn_mfma_f32_16x16x32_f16(a[i], bb[j], acc[i][j], 0, 0, 0);
        }
    };

    loadW(0);
    stageA(0, 0);
    writeW();
    __syncthreads();

    int cb = 0;
    for (int k0 = 64; k0 < K; k0 += 64) {
        loadW(k0);
        stageA(k0, cb ^ 1);
        compute(cb);
        __syncthreads();
        writeW();
        __syncthreads();
        cb ^= 1;
    }
    compute(cb);

    f16* Yrow = Y + (size_t)(rowbeg + mtile) * Nld + n0;
    #pragma unroll
    for (int i = 0; i < 4; ++i)
        #pragma unroll
        for (int j = 0; j < 4; ++j)
            #pragma unroll
            for (int r = 0; r < 4; ++r) {
                int m = wm + i * 16 + lquad * 4 + r;
                if (m < Mblk)
                    Yrow[(size_t)m * Nld + wn + j * 16 + lrow] = (f16)acc[i][j][r];
            }
}

// ---------------------------------------------------------------------------
// Combine: out[t] = ys[t] + sum_k w_k * y[row(t,k)]
// ---------------------------------------------------------------------------
__global__ void k_combine(const f16* __restrict__ y, const f16* __restrict__ ys,
                          const int* __restrict__ slot_e, const int* __restrict__ slot_pos,
                          const float* __restrict__ slot_w, const int* __restrict__ offsets,
                          float* __restrict__ out)
{
    int t = blockIdx.x, i = threadIdx.x;
    size_t col = (size_t)i * 4;
    f16x4 s = *(const f16x4*)(ys + (size_t)t * HDIM + col);
    float a0 = (float)s[0], a1 = (float)s[1], a2 = (float)s[2], a3 = (float)s[3];
    #pragma unroll
    for (int k = 0; k < TOPK; ++k) {
        int sidx = t * TOPK + k;
        int p = slot_pos[sidx];
        if (p < CAPC) {
            int row = offsets[slot_e[sidx]] + p;
            float w = slot_w[sidx];
            f16x4 v = *(const f16x4*)(y + (size_t)row * HDIM + col);
            a0 += w * (float)v[0]; a1 += w * (float)v[1];
            a2 += w * (float)v[2]; a3 += w * (float)v[3];
        }
    }
    float4 o = {a0, a1, a2, a3};
    *(float4*)(out + (size_t)t * HDIM + col) = o;
}

extern "C" void kernel_launch(void* const* d_in, const int* in_sizes, int n_in,
                              void* d_out, int out_size, void* d_ws, size_t ws_size,
                              hipStream_t stream)
{
    const float* x  = (const float*)d_in[0];
    const float* gw = (const float*)d_in[1];
    const float* eb = (const float*)d_in[2];
    const float* w1 = (const float*)d_in[3];
    const float* w2 = (const float*)d_in[4];
    const float* w3 = (const float*)d_in[5];
    const float* sg = (const float*)d_in[6];
    const float* su = (const float*)d_in[7];
    const float* sd = (const float*)d_in[8];
    float* out = (float*)d_out;

    char* p = (char*)d_ws;
    size_t off = 0;
    auto alloc = [&](size_t n) { void* r = p + off; off = (off + n + 255) & ~(size_t)255; return r; };
    int*   counts   = (int*)alloc(NEXP * 4);
    int*   offsets  = (int*)alloc(NEXP * 4);
    int*   slot_e   = (int*)alloc((size_t)T_TOK * TOPK * 4);
    int*   slot_pos = (int*)alloc((size_t)T_TOK * TOPK * 4);
    float* slot_w   = (float*)alloc((size_t)T_TOK * TOPK * 4);
    int*   row_tok  = (int*)alloc((size_t)T_TOK * TOPK * 4);
    float* logits   = (float*)alloc((size_t)T_TOK * NEXP * 4);          // 512 KB
    f16*   xb  = (f16*)alloc((size_t)T_TOK * HDIM * 2);                 // 4 MB
    f16*   h   = (f16*)alloc((size_t)T_TOK * TOPK * FDIM * 2);          // 16 MB
    f16*   y   = (f16*)alloc((size_t)T_TOK * TOPK * HDIM * 2);          // 32 MB
    f16*   hs  = (f16*)alloc((size_t)T_TOK * 2 * FDIM * 2);             // 4 MB
    f16*   ys  = (f16*)alloc((size_t)T_TOK * HDIM * 2);                 // 4 MB

    hipMemsetAsync(counts, 0, NEXP * 4, stream);

    // routing path
    const int XW8 = T_TOK * HDIM / 8;            // 262144
    k_cvt<<<(XW8 + 255) / 256, 256, 0, stream>>>(x, xb, XW8);
    k_logits<<<T_TOK / 8, 256, 0, stream>>>(x, gw, logits);
    k_topk<<<T_TOK, 64, 0, stream>>>(logits, eb, counts, slot_e, slot_pos, slot_w);
    k_scan<<<1, 64, 0, stream>>>(counts, offsets);
    k_rowmap<<<(T_TOK * TOPK + 255) / 256, 256, 0, stream>>>(slot_e, slot_pos, offsets, row_tok);

    // gate-up GEMMs (weights fp32, conversion fused into staging)
    // expert grid: (ntile, expert, mtile) -> active blocks contiguous in
    // linear dispatch-id space (dead mtile-blocks trail).
    k_gateup<<<dim3(FDIM / 64, NEXP, CAPC / 128), 256, 0, stream>>>(
        xb, w1, w3, h, offsets, counts, row_tok, HDIM, FDIM, 0, 1);
    k_gateup<<<dim3((2 * FDIM) / 64, T_TOK / 128, 1), 256, 0, stream>>>(
        xb, sg, su, hs, offsets, counts, row_tok, HDIM, 2 * FDIM, T_TOK, 0);

    // down GEMMs
    k_down<<<dim3(HDIM / 128, NEXP, CAPC / 128), 256, 0, stream>>>(
        h, w2, y, offsets, counts, FDIM, HDIM, 0, 1);
    k_down<<<dim3(HDIM / 128, T_TOK / 128, 1), 256, 0, stream>>>(
        hs, sd, ys, offsets, counts, 2 * FDIM, HDIM, T_TOK, 0);

    k_combine<<<T_TOK, 256, 0, stream>>>(y, ys, slot_e, slot_pos, slot_w, offsets, out);
}